// Round 1
// baseline (49777.795 us; speedup 1.0000x reference)
//
#include <hip/hip_runtime.h>
#include <math.h>

#define T_LEN 76800
#define T_MEL 300
#define B_N 4

// ---------------- prep kernels ----------------

// cu0[b][o][m] = sum_i up_in_w[o][i] * c[b][i][m]
__global__ void cu0_kernel(const float* __restrict__ c, const float* __restrict__ up_in_w,
                           float* __restrict__ cu0) {
    int idx = blockIdx.x * 256 + threadIdx.x;
    if (idx >= B_N * 80 * T_MEL) return;
    int m = idx % T_MEL; int rest = idx / T_MEL; int o = rest % 80; int b = rest / 80;
    const float* crow = c + (size_t)(b * 80) * T_MEL;
    const float* wrow = up_in_w + o * 80;
    float acc = 0.f;
    for (int i = 0; i < 80; ++i) acc = fmaf(wrow[i], crow[(size_t)i * T_MEL + m], acc);
    cu0[idx] = acc;
}

// composite 33-tap filter of the 4 upsample convs, prefix sums, and exact edge vectors.
// filt layout: [0..33] = P prefix sums (P[33]=Ksum), [34] = Ksum, [40..55] = E_L, [56..71] = E_R
__global__ void filt_kernel(const float* __restrict__ up_conv_w, float* __restrict__ filt) {
    if (threadIdx.x != 0 || blockIdx.x != 0) return;
    float F[33], tmp[33];
    for (int j = 0; j < 9; ++j) F[j] = up_conv_w[j];
    int len = 9;
    for (int s = 1; s < 4; ++s) {
        const float* w = up_conv_w + s * 9;
        int nl = len + 8;
        for (int j = 0; j < nl; ++j) {
            float acc = 0.f;
            for (int a = 0; a < 9; ++a) { int bi = j - a; if (bi >= 0 && bi < len) acc += w[a] * F[bi]; }
            tmp[j] = acc;
        }
        for (int j = 0; j < nl; ++j) F[j] = tmp[j];
        len = nl;
    }
    float run = 0.f;
    for (int n = 0; n < 33; ++n) { filt[n] = run; run += F[n]; }
    filt[33] = run; filt[34] = run;
    const float* w1 = up_conv_w + 0;  const float* w2 = up_conv_w + 9;
    const float* w3 = up_conv_w + 18; const float* w4 = up_conv_w + 27;
    // left edge: input = 1 for u>=0 (frame 0), 0 for u<0 (stage zero-padding)
    {
        float y1[28], y2[24], y3[20];
        for (int u = 0; u < 28; ++u) { float a = 0; for (int k = 0; k < 9; ++k) { int v = u + k - 4; if (v >= 0) a += w1[k]; } y1[u] = a; }
        for (int u = 0; u < 24; ++u) { float a = 0; for (int k = 0; k < 9; ++k) { int v = u + k - 4; if (v >= 0) a += w2[k] * y1[v]; } y2[u] = a; }
        for (int u = 0; u < 20; ++u) { float a = 0; for (int k = 0; k < 9; ++k) { int v = u + k - 4; if (v >= 0) a += w3[k] * y2[v]; } y3[u] = a; }
        for (int t = 0; t < 16; ++t) { float a = 0; for (int k = 0; k < 9; ++k) { int v = t + k - 4; if (v >= 0) a += w4[k] * y3[v]; } filt[40 + t] = a; }
    }
    // right edge: idx 0..43 maps to u = T-44+idx; input = 1 for u<=T-1 (frame 299), 0 for u>=T
    {
        float z1[44], z2[44], z3[44];
        for (int u = 0; u < 44; ++u) { float a = 0; for (int k = 0; k < 9; ++k) { int v = u + k - 4; if (v <= 43) a += w1[k]; } z1[u] = a; }
        for (int u = 0; u < 44; ++u) { float a = 0; for (int k = 0; k < 9; ++k) { int v = u + k - 4; if (v <= 43) a += w2[k] * z1[v < 0 ? 0 : v]; } z2[u] = a; }
        for (int u = 0; u < 44; ++u) { float a = 0; for (int k = 0; k < 9; ++k) { int v = u + k - 4; if (v <= 43) a += w3[k] * z2[v < 0 ? 0 : v]; } z3[u] = a; }
        for (int j = 0; j < 16; ++j) {
            int u = 28 + j; float a = 0;
            for (int k = 0; k < 9; ++k) { int v = u + k - 4; if (v <= 43) a += w4[k] * z3[v < 0 ? 0 : v]; }
            filt[56 + j] = a;
        }
    }
}

// g[i][b][o][m] = sum_c blk_aux_w[i][o][c] * cu0[b][c][m]
__global__ void g_kernel(const float* __restrict__ cu0, const float* __restrict__ aux_w,
                         float* __restrict__ g) {
    int idx = blockIdx.x * 256 + threadIdx.x;
    if (idx >= 30 * B_N * 128 * T_MEL) return;
    int m = idx % T_MEL; int rest = idx / T_MEL; int o = rest % 128; rest /= 128;
    int b = rest % B_N; int i = rest / B_N;
    const float* wrow = aux_w + ((size_t)i * 128 + o) * 80;
    const float* crow = cu0 + (size_t)(b * 80) * T_MEL + m;
    float acc = 0.f;
    for (int cc = 0; cc < 80; ++cc) acc = fmaf(wrow[cc], crow[(size_t)cc * T_MEL], acc);
    g[idx] = acc;
}

// x0[b][o][t] = first_w[o] * noise[b][t] + first_b[o]
__global__ void first_kernel(const float* __restrict__ noise, const float* __restrict__ fw,
                             const float* __restrict__ fb, float* __restrict__ x) {
    int idx = blockIdx.x * 256 + threadIdx.x;
    if (idx >= B_N * 64 * T_LEN) return;
    int t = idx % T_LEN; int rest = idx / T_LEN; int o = rest % 64; int b = rest / 64;
    x[idx] = fmaf(fw[o], noise[(size_t)b * T_LEN + t], fb[o]);
}

// ---------------- main residual block ----------------
// 256 threads = 4 waves. lane = t (tile of 64 t). Phase 1: each wave computes 32 of
// 128 h-rows (dilated conv + bias + aux interp) -> LDS. Phase 2: gate -> z in LDS.
// Phase 3: waves 0,1 = skip rows, waves 2,3 = out rows (residual update).
__global__ __launch_bounds__(256) void block_kernel(
    const float* __restrict__ x_in, float* __restrict__ x_out,
    float* __restrict__ skip, const float* __restrict__ g,
    const float* __restrict__ filt,
    const float* __restrict__ conv_w, const float* __restrict__ conv_b,
    const float* __restrict__ skip_w, const float* __restrict__ skip_b,
    const float* __restrict__ out_w, const float* __restrict__ out_b,
    int d, int first) {
    __shared__ float lds_h[128][64];
    __shared__ float lds_z[64][64];
    const int tid = threadIdx.x, wave = tid >> 6, lane = tid & 63;
    const int b = blockIdx.y;
    const int t = blockIdx.x * 64 + lane;

    // aux interpolation coefficients for this t
    int m = t >> 8, r = t & 255;
    float c0, c1, c2; int i0, i1, i2;
    if (t < 16)               { c0 = filt[40 + t];              i0 = 0;   c1 = 0; i1 = 0;   c2 = 0; i2 = 0; }
    else if (t >= T_LEN - 16) { c0 = filt[56 + (t - (T_LEN-16))]; i0 = 299; c1 = 0; i1 = 299; c2 = 0; i2 = 299; }
    else if (r < 16)  { float bl = filt[16 - r];              c0 = filt[34] - bl; i0 = m; c1 = bl; i1 = m - 1; c2 = 0;  i2 = m; }
    else if (r > 239) { float bh = filt[34] - filt[272 - r];  c0 = filt[34] - bh; i0 = m; c1 = 0;  i1 = m;     c2 = bh; i2 = m + 1; }
    else              { c0 = filt[34]; i0 = m; c1 = 0; i1 = m; c2 = 0; i2 = m; }

    float acc[32];
    {
        const float* gb = g + ((size_t)b * 128 + wave * 32) * T_MEL;
        #pragma unroll
        for (int oo = 0; oo < 32; ++oo) {
            const float* go = gb + (size_t)oo * T_MEL;
            acc[oo] = conv_b[wave * 32 + oo] + c0 * go[i0] + c1 * go[i1] + c2 * go[i2];
        }
    }
    const float* xb = x_in + (size_t)b * 64 * T_LEN;
    const int tm = t - d, tp = t + d;
    const bool okm = tm >= 0, okp = tp < T_LEN;
    for (int i = 0; i < 64; ++i) {
        const float* xr = xb + (size_t)i * T_LEN;
        float xm = okm ? xr[tm] : 0.f;
        float x0 = xr[t];
        float xp = okp ? xr[tp] : 0.f;
        const float* wp_ = conv_w + ((size_t)(wave * 32) * 64 + i) * 3;
        #pragma unroll
        for (int oo = 0; oo < 32; ++oo) {
            const float* w3 = wp_ + (size_t)oo * 64 * 3;
            acc[oo] = fmaf(w3[0], xm, acc[oo]);
            acc[oo] = fmaf(w3[1], x0, acc[oo]);
            acc[oo] = fmaf(w3[2], xp, acc[oo]);
        }
    }
    #pragma unroll
    for (int oo = 0; oo < 32; ++oo) lds_h[wave * 32 + oo][lane] = acc[oo];
    __syncthreads();

    #pragma unroll
    for (int rep = 0; rep < 16; ++rep) {
        int idx = tid + rep * 256;
        int cch = idx >> 6, tt = idx & 63;
        float xa = lds_h[cch][tt];
        float xg = lds_h[cch + 64][tt];
        lds_z[cch][tt] = tanhf(xa) * (1.f / (1.f + expf(-xg)));
    }
    __syncthreads();

    const int isOut = wave >> 1;
    const int row0 = (wave & 1) * 32;
    const float* W  = isOut ? out_w : skip_w;
    const float* Bv = isOut ? out_b : skip_b;
    float acc2[32];
    #pragma unroll
    for (int rr = 0; rr < 32; ++rr) acc2[rr] = Bv[row0 + rr];
    for (int cch = 0; cch < 64; ++cch) {
        float zc = lds_z[cch][lane];
        const float* wc = W + (size_t)row0 * 64 + cch;
        #pragma unroll
        for (int rr = 0; rr < 32; ++rr) acc2[rr] = fmaf(wc[(size_t)rr * 64], zc, acc2[rr]);
    }
    if (isOut) {
        #pragma unroll
        for (int rr = 0; rr < 32; ++rr) {
            size_t off = ((size_t)b * 64 + row0 + rr) * T_LEN + t;
            x_out[off] = (acc2[rr] + x_in[off]) * 0.25f;
        }
    } else {
        #pragma unroll
        for (int rr = 0; rr < 32; ++rr) {
            size_t off = ((size_t)b * 64 + row0 + rr) * T_LEN + t;
            skip[off] = first ? acc2[rr] : (skip[off] + acc2[rr]);
        }
    }
}

// ---------------- epilogue ----------------
__global__ void final_kernel(const float* __restrict__ skip,
                             const float* __restrict__ l1w, const float* __restrict__ l1b,
                             const float* __restrict__ l2w, const float* __restrict__ l2b,
                             float* __restrict__ out) {
    int idx = blockIdx.x * 256 + threadIdx.x;
    if (idx >= B_N * T_LEN) return;
    int t = idx % T_LEN; int b = idx / T_LEN;
    const float scale = 0.18257418583505536f; // sqrt(1/30)
    float rbuf[64];
    const float* srow = skip + (size_t)b * 64 * T_LEN + t;
    #pragma unroll
    for (int s = 0; s < 64; ++s) {
        float v = srow[(size_t)s * T_LEN] * scale;
        rbuf[s] = v > 0.f ? v : 0.f;
    }
    float oacc = l2b[0];
    for (int cch = 0; cch < 64; ++cch) {
        float a = l1b[cch];
        const float* wrow = l1w + (size_t)cch * 64;
        #pragma unroll
        for (int s = 0; s < 64; ++s) a = fmaf(wrow[s], rbuf[s], a);
        a = a > 0.f ? a : 0.f;
        oacc = fmaf(l2w[cch], a, oacc);
    }
    out[idx] = oacc;
}

// ---------------- launch ----------------
extern "C" void kernel_launch(void* const* d_in, const int* in_sizes, int n_in,
                              void* d_out, int out_size, void* d_ws, size_t ws_size,
                              hipStream_t stream) {
    const float* c          = (const float*)d_in[0];
    const float* noise      = (const float*)d_in[1];
    const float* first_w    = (const float*)d_in[2];
    const float* first_b    = (const float*)d_in[3];
    const float* up_in_w    = (const float*)d_in[4];
    const float* up_conv_w  = (const float*)d_in[5];
    const float* blk_conv_w = (const float*)d_in[6];
    const float* blk_conv_b = (const float*)d_in[7];
    const float* blk_aux_w  = (const float*)d_in[8];
    const float* blk_out_w  = (const float*)d_in[9];
    const float* blk_out_b  = (const float*)d_in[10];
    const float* blk_skip_w = (const float*)d_in[11];
    const float* blk_skip_b = (const float*)d_in[12];
    const float* last1_w    = (const float*)d_in[13];
    const float* last1_b    = (const float*)d_in[14];
    const float* last2_w    = (const float*)d_in[15];
    const float* last2_b    = (const float*)d_in[16];
    float* out = (float*)d_out;
    float* ws  = (float*)d_ws;

    size_t off = 0;
    float* cu0  = ws + off; off += 96256;                       // 4*80*300 rounded
    float* g    = ws + off; off += 30ull * 4 * 128 * T_MEL;     // 4,608,000
    float* filt = ws + off; off += 128;
    float* xA   = ws + off; off += 4ull * 64 * T_LEN;
    float* xB   = ws + off; off += 4ull * 64 * T_LEN;
    float* skip = ws + off; off += 4ull * 64 * T_LEN;
    if (ws_size < off * sizeof(float)) return;  // not enough scratch; bail cleanly

    hipLaunchKernelGGL(cu0_kernel, dim3((B_N * 80 * T_MEL + 255) / 256), dim3(256), 0, stream,
                       c, up_in_w, cu0);
    hipLaunchKernelGGL(filt_kernel, dim3(1), dim3(64), 0, stream, up_conv_w, filt);
    hipLaunchKernelGGL(g_kernel, dim3((30 * B_N * 128 * T_MEL + 255) / 256), dim3(256), 0, stream,
                       cu0, blk_aux_w, g);
    hipLaunchKernelGGL(first_kernel, dim3((B_N * 64 * T_LEN + 255) / 256), dim3(256), 0, stream,
                       noise, first_w, first_b, xA);

    for (int i = 0; i < 30; ++i) {
        int dd = 1 << (i % 10);
        const float* xin = (i & 1) ? xB : xA;
        float* xout      = (i & 1) ? xA : xB;
        hipLaunchKernelGGL(block_kernel, dim3(T_LEN / 64, B_N), dim3(256), 0, stream,
                           xin, xout, skip,
                           g + (size_t)i * 4 * 128 * T_MEL, filt,
                           blk_conv_w + (size_t)i * 128 * 64 * 3,
                           blk_conv_b + (size_t)i * 128,
                           blk_skip_w + (size_t)i * 64 * 64,
                           blk_skip_b + (size_t)i * 64,
                           blk_out_w + (size_t)i * 64 * 64,
                           blk_out_b + (size_t)i * 64,
                           dd, i == 0 ? 1 : 0);
    }

    hipLaunchKernelGGL(final_kernel, dim3((B_N * T_LEN + 255) / 256), dim3(256), 0, stream,
                       skip, last1_w, last1_b, last2_w, last2_b, out);
}

// Round 2
// 8474.615 us; speedup vs baseline: 5.8738x; 5.8738x over previous
//
#include <hip/hip_runtime.h>
#include <math.h>

#define T_LEN 76800
#define T_MEL 300
#define B_N 4

// ---------------- prep kernels ----------------

// cu0[b][o][m] = sum_i up_in_w[o][i] * c[b][i][m]
__global__ void cu0_kernel(const float* __restrict__ c, const float* __restrict__ up_in_w,
                           float* __restrict__ cu0) {
    int idx = blockIdx.x * 256 + threadIdx.x;
    if (idx >= B_N * 80 * T_MEL) return;
    int m = idx % T_MEL; int rest = idx / T_MEL; int o = rest % 80; int b = rest / 80;
    const float* crow = c + (size_t)(b * 80) * T_MEL;
    const float* wrow = up_in_w + o * 80;
    float acc = 0.f;
    for (int i = 0; i < 80; ++i) acc = fmaf(wrow[i], crow[(size_t)i * T_MEL + m], acc);
    cu0[idx] = acc;
}

// composite 33-tap filter of the 4 upsample convs, prefix sums, and exact edge vectors.
// filt layout: [0..33] = P prefix sums (P[33]=Ksum), [34] = Ksum, [40..55] = E_L, [56..71] = E_R
__global__ void filt_kernel(const float* __restrict__ up_conv_w, float* __restrict__ filt) {
    if (threadIdx.x != 0 || blockIdx.x != 0) return;
    float F[33], tmp[33];
    for (int j = 0; j < 9; ++j) F[j] = up_conv_w[j];
    int len = 9;
    for (int s = 1; s < 4; ++s) {
        const float* w = up_conv_w + s * 9;
        int nl = len + 8;
        for (int j = 0; j < nl; ++j) {
            float acc = 0.f;
            for (int a = 0; a < 9; ++a) { int bi = j - a; if (bi >= 0 && bi < len) acc += w[a] * F[bi]; }
            tmp[j] = acc;
        }
        for (int j = 0; j < nl; ++j) F[j] = tmp[j];
        len = nl;
    }
    float run = 0.f;
    for (int n = 0; n < 33; ++n) { filt[n] = run; run += F[n]; }
    filt[33] = run; filt[34] = run;
    const float* w1 = up_conv_w + 0;  const float* w2 = up_conv_w + 9;
    const float* w3 = up_conv_w + 18; const float* w4 = up_conv_w + 27;
    {
        float y1[28], y2[24], y3[20];
        for (int u = 0; u < 28; ++u) { float a = 0; for (int k = 0; k < 9; ++k) { int v = u + k - 4; if (v >= 0) a += w1[k]; } y1[u] = a; }
        for (int u = 0; u < 24; ++u) { float a = 0; for (int k = 0; k < 9; ++k) { int v = u + k - 4; if (v >= 0) a += w2[k] * y1[v]; } y2[u] = a; }
        for (int u = 0; u < 20; ++u) { float a = 0; for (int k = 0; k < 9; ++k) { int v = u + k - 4; if (v >= 0) a += w3[k] * y2[v]; } y3[u] = a; }
        for (int t = 0; t < 16; ++t) { float a = 0; for (int k = 0; k < 9; ++k) { int v = t + k - 4; if (v >= 0) a += w4[k] * y3[v]; } filt[40 + t] = a; }
    }
    {
        float z1[44], z2[44], z3[44];
        for (int u = 0; u < 44; ++u) { float a = 0; for (int k = 0; k < 9; ++k) { int v = u + k - 4; if (v <= 43) a += w1[k]; } z1[u] = a; }
        for (int u = 0; u < 44; ++u) { float a = 0; for (int k = 0; k < 9; ++k) { int v = u + k - 4; if (v <= 43) a += w2[k] * z1[v < 0 ? 0 : v]; } z2[u] = a; }
        for (int u = 0; u < 44; ++u) { float a = 0; for (int k = 0; k < 9; ++k) { int v = u + k - 4; if (v <= 43) a += w3[k] * z2[v < 0 ? 0 : v]; } z3[u] = a; }
        for (int j = 0; j < 16; ++j) {
            int u = 28 + j; float a = 0;
            for (int k = 0; k < 9; ++k) { int v = u + k - 4; if (v <= 43) a += w4[k] * z3[v < 0 ? 0 : v]; }
            filt[56 + j] = a;
        }
    }
}

// g[i][b][o][m] = sum_c blk_aux_w[i][o][c] * cu0[b][c][m]
__global__ void g_kernel(const float* __restrict__ cu0, const float* __restrict__ aux_w,
                         float* __restrict__ g) {
    int idx = blockIdx.x * 256 + threadIdx.x;
    if (idx >= 30 * B_N * 128 * T_MEL) return;
    int m = idx % T_MEL; int rest = idx / T_MEL; int o = rest % 128; rest /= 128;
    int b = rest % B_N; int i = rest / B_N;
    const float* wrow = aux_w + ((size_t)i * 128 + o) * 80;
    const float* crow = cu0 + (size_t)(b * 80) * T_MEL + m;
    float acc = 0.f;
    for (int cc = 0; cc < 80; ++cc) acc = fmaf(wrow[cc], crow[(size_t)cc * T_MEL], acc);
    g[idx] = acc;
}

// x0[b][o][t] = first_w[o] * noise[b][t] + first_b[o]
__global__ void first_kernel(const float* __restrict__ noise, const float* __restrict__ fw,
                             const float* __restrict__ fb, float* __restrict__ x) {
    int idx = blockIdx.x * 256 + threadIdx.x;
    if (idx >= B_N * 64 * T_LEN) return;
    int t = idx % T_LEN; int rest = idx / T_LEN; int o = rest % 64; int b = rest / 64;
    x[idx] = fmaf(fw[o], noise[(size_t)b * T_LEN + t], fb[o]);
}

// ---------------- main residual block: register-tiled GEMM form ----------------
// Block tile: 128 output rows x 128 t. 256 threads = 16x16. Thread tile 8x8:
// rows {4ty..4ty+3} U {64+4ty..+3}  (pairs (o,o+64) in-register for gating)
// cols {4tx..4tx+3} U {64+4tx..+3}
// Phase 1: H = W[128][192] * X[192][T]  (k = i*3+tap, X row = x shifted by (tap-1)*d)
// Gate in-register -> z -> LDS. Phase 2: [skip;out] = W2[128][64] * Z[64][T].
__global__ __launch_bounds__(256) void block_kernel(
    const float* __restrict__ x_in, float* __restrict__ x_out,
    float* __restrict__ skip, const float* __restrict__ g,
    const float* __restrict__ filt,
    const float* __restrict__ conv_w, const float* __restrict__ conv_b,
    const float* __restrict__ skip_w, const float* __restrict__ skip_b,
    const float* __restrict__ out_w, const float* __restrict__ out_b,
    int d, int first) {
    __shared__ float Wlt[32][132];     // transposed weight chunk [k][row], pad 132 (16B-aligned rows)
    __shared__ float XZ[64][128];      // phase1: X chunk rows 0..31 ; phase2: Z rows 0..63
    __shared__ float glm[128], gll[128], glr[128], bl1[128], bl2[128];

    const int tid = threadIdx.x;
    const int tx = tid & 15, ty = tid >> 4;
    const int b = blockIdx.y;
    const int t0 = blockIdx.x * 128;
    const int m0 = t0 >> 8;

    // ---- stage g columns + biases ----
    if (tid < 128) {
        int o = tid;
        const float* gb = g + ((size_t)b * 128 + o) * T_MEL;
        int ml = m0 > 0 ? m0 - 1 : 0;
        int mr = m0 < 299 ? m0 + 1 : 299;
        glm[o] = gb[m0]; gll[o] = gb[ml]; glr[o] = gb[mr];
        bl1[o] = conv_b[o];
    } else {
        int o = tid - 128;
        bl2[o] = (o < 64) ? skip_b[o] : out_b[o - 64];
    }
    __syncthreads();

    // ---- per-column aux interpolation coefficients ----
    float am[8], al[8], ar[8];
    const float K = filt[34];
    #pragma unroll
    for (int cc = 0; cc < 8; ++cc) {
        int col = (cc < 4) ? 4 * tx + cc : 64 + 4 * tx + (cc - 4);
        int t = t0 + col;
        int r = t & 255;
        float Am = K, Al = 0.f, Ar = 0.f;
        if (t < 16)                { Am = filt[40 + t]; }
        else if (t >= T_LEN - 16)  { Am = filt[56 + (t - (T_LEN - 16))]; }
        else if (r < 16)  { float blv = filt[16 - r];       Am = K - blv; Al = blv; }
        else if (r > 239) { float bh = K - filt[272 - r];   Am = K - bh;  Ar = bh; }
        am[cc] = Am; al[cc] = Al; ar[cc] = Ar;
    }

    // ---- acc init: bias + aux ----
    float acc[8][8];
    #pragma unroll
    for (int rr = 0; rr < 8; ++rr) {
        int row = (rr < 4) ? 4 * ty + rr : 64 + 4 * ty + (rr - 4);
        float bia = bl1[row], gm = glm[row], gl_ = gll[row], gr = glr[row];
        #pragma unroll
        for (int cc = 0; cc < 8; ++cc)
            acc[rr][cc] = bia + am[cc] * gm + al[cc] * gl_ + ar[cc] * gr;
    }

    const float* xbp = x_in + (size_t)b * 64 * T_LEN;

    // ---- phase 1: 6 chunks of kc=32 over K=192 ----
    for (int ch = 0; ch < 6; ++ch) {
        const int k0 = ch * 32;
        // stage Wlt[k][o] = conv_w[o][k0+k]
        #pragma unroll
        for (int it = 0; it < 4; ++it) {
            int q = it * 256 + tid;
            int o = q >> 3, kq = q & 7;
            const float4 w4 = *(const float4*)(conv_w + (size_t)o * 192 + k0 + 4 * kq);
            Wlt[4 * kq + 0][o] = w4.x; Wlt[4 * kq + 1][o] = w4.y;
            Wlt[4 * kq + 2][o] = w4.z; Wlt[4 * kq + 3][o] = w4.w;
        }
        // stage X chunk: XZ[k][t] = x[i][t0 + t + (tap-1)*d], k = k0.. (i = k/3, tap = k%3)
        #pragma unroll
        for (int it = 0; it < 4; ++it) {
            int q = it * 256 + tid;
            int row = q >> 5, quad = q & 31;
            int kk = k0 + row;
            int i = kk / 3, tap = kk - 3 * i;
            int shift = (tap - 1) * d;
            int tsrc = t0 + 4 * quad + shift;
            const float* xr = xbp + (size_t)i * T_LEN;
            float4 v;
            if (((shift & 3) == 0) && tsrc >= 0 && tsrc + 3 < T_LEN) {
                v = *(const float4*)(xr + tsrc);
            } else {
                v.x = (tsrc + 0 >= 0 && tsrc + 0 < T_LEN) ? xr[tsrc + 0] : 0.f;
                v.y = (tsrc + 1 >= 0 && tsrc + 1 < T_LEN) ? xr[tsrc + 1] : 0.f;
                v.z = (tsrc + 2 >= 0 && tsrc + 2 < T_LEN) ? xr[tsrc + 2] : 0.f;
                v.w = (tsrc + 3 >= 0 && tsrc + 3 < T_LEN) ? xr[tsrc + 3] : 0.f;
            }
            *(float4*)&XZ[row][4 * quad] = v;
        }
        __syncthreads();
        #pragma unroll 2
        for (int k = 0; k < 32; ++k) {
            float4 wa0 = *(const float4*)&Wlt[k][4 * ty];
            float4 wa1 = *(const float4*)&Wlt[k][64 + 4 * ty];
            float4 xv0 = *(const float4*)&XZ[k][4 * tx];
            float4 xv1 = *(const float4*)&XZ[k][64 + 4 * tx];
            float wv[8] = {wa0.x, wa0.y, wa0.z, wa0.w, wa1.x, wa1.y, wa1.z, wa1.w};
            float xv[8] = {xv0.x, xv0.y, xv0.z, xv0.w, xv1.x, xv1.y, xv1.z, xv1.w};
            #pragma unroll
            for (int rr = 0; rr < 8; ++rr)
                #pragma unroll
                for (int cc = 0; cc < 8; ++cc)
                    acc[rr][cc] = fmaf(wv[rr], xv[cc], acc[rr][cc]);
        }
        __syncthreads();
    }

    // ---- gate: z = tanh(h_a) * sigmoid(h_b), pairs are in-register ----
    #pragma unroll
    for (int rr = 0; rr < 4; ++rr) {
        float zv[8];
        #pragma unroll
        for (int cc = 0; cc < 8; ++cc) {
            float xa = acc[rr][cc];
            float xg = acc[rr + 4][cc];
            zv[cc] = tanhf(xa) * (1.f / (1.f + expf(-xg)));
        }
        int zr = 4 * ty + rr;
        *(float4*)&XZ[zr][4 * tx]      = make_float4(zv[0], zv[1], zv[2], zv[3]);
        *(float4*)&XZ[zr][64 + 4 * tx] = make_float4(zv[4], zv[5], zv[6], zv[7]);
    }

    // ---- phase 2: [skip(0..63); out(64..127)] = W2[128][64] * Z ----
    float acc2[8][8];
    #pragma unroll
    for (int rr = 0; rr < 8; ++rr) {
        int row = (rr < 4) ? 4 * ty + rr : 64 + 4 * ty + (rr - 4);
        float bia = bl2[row];
        #pragma unroll
        for (int cc = 0; cc < 8; ++cc) acc2[rr][cc] = bia;
    }
    for (int ch = 0; ch < 2; ++ch) {
        const int k0 = ch * 32;
        #pragma unroll
        for (int it = 0; it < 4; ++it) {
            int q = it * 256 + tid;
            int o = q >> 3, kq = q & 7;
            const float* src = (o < 64) ? (skip_w + (size_t)o * 64 + k0 + 4 * kq)
                                        : (out_w + (size_t)(o - 64) * 64 + k0 + 4 * kq);
            const float4 w4 = *(const float4*)src;
            Wlt[4 * kq + 0][o] = w4.x; Wlt[4 * kq + 1][o] = w4.y;
            Wlt[4 * kq + 2][o] = w4.z; Wlt[4 * kq + 3][o] = w4.w;
        }
        __syncthreads();
        #pragma unroll 2
        for (int k = 0; k < 32; ++k) {
            float4 wa0 = *(const float4*)&Wlt[k][4 * ty];
            float4 wa1 = *(const float4*)&Wlt[k][64 + 4 * ty];
            float4 zv0 = *(const float4*)&XZ[k0 + k][4 * tx];
            float4 zv1 = *(const float4*)&XZ[k0 + k][64 + 4 * tx];
            float wv[8] = {wa0.x, wa0.y, wa0.z, wa0.w, wa1.x, wa1.y, wa1.z, wa1.w};
            float zv[8] = {zv0.x, zv0.y, zv0.z, zv0.w, zv1.x, zv1.y, zv1.z, zv1.w};
            #pragma unroll
            for (int rr = 0; rr < 8; ++rr)
                #pragma unroll
                for (int cc = 0; cc < 8; ++cc)
                    acc2[rr][cc] = fmaf(wv[rr], zv[cc], acc2[rr][cc]);
        }
        __syncthreads();
    }

    // ---- epilogue: skip accumulate + residual out ----
    #pragma unroll
    for (int rr = 0; rr < 4; ++rr) {
        int s = 4 * ty + rr;
        size_t base = ((size_t)b * 64 + s) * T_LEN + t0;
        float4* sp0 = (float4*)(skip + base + 4 * tx);
        float4* sp1 = (float4*)(skip + base + 64 + 4 * tx);
        float4 v0 = make_float4(acc2[rr][0], acc2[rr][1], acc2[rr][2], acc2[rr][3]);
        float4 v1 = make_float4(acc2[rr][4], acc2[rr][5], acc2[rr][6], acc2[rr][7]);
        if (!first) {
            float4 o0 = *sp0, o1 = *sp1;
            v0.x += o0.x; v0.y += o0.y; v0.z += o0.z; v0.w += o0.w;
            v1.x += o1.x; v1.y += o1.y; v1.z += o1.z; v1.w += o1.w;
        }
        *sp0 = v0; *sp1 = v1;
    }
    #pragma unroll
    for (int rr = 4; rr < 8; ++rr) {
        int o = 4 * ty + (rr - 4);
        size_t base = ((size_t)b * 64 + o) * T_LEN + t0;
        const float4 xi0 = *(const float4*)(x_in + base + 4 * tx);
        const float4 xi1 = *(const float4*)(x_in + base + 64 + 4 * tx);
        float4 v0, v1;
        v0.x = (acc2[rr][0] + xi0.x) * 0.25f; v0.y = (acc2[rr][1] + xi0.y) * 0.25f;
        v0.z = (acc2[rr][2] + xi0.z) * 0.25f; v0.w = (acc2[rr][3] + xi0.w) * 0.25f;
        v1.x = (acc2[rr][4] + xi1.x) * 0.25f; v1.y = (acc2[rr][5] + xi1.y) * 0.25f;
        v1.z = (acc2[rr][6] + xi1.z) * 0.25f; v1.w = (acc2[rr][7] + xi1.w) * 0.25f;
        *(float4*)(x_out + base + 4 * tx) = v0;
        *(float4*)(x_out + base + 64 + 4 * tx) = v1;
    }
}

// ---------------- epilogue ----------------
__global__ void final_kernel(const float* __restrict__ skip,
                             const float* __restrict__ l1w, const float* __restrict__ l1b,
                             const float* __restrict__ l2w, const float* __restrict__ l2b,
                             float* __restrict__ out) {
    int idx = blockIdx.x * 256 + threadIdx.x;
    if (idx >= B_N * T_LEN) return;
    int t = idx % T_LEN; int b = idx / T_LEN;
    const float scale = 0.18257418583505536f; // sqrt(1/30)
    float rbuf[64];
    const float* srow = skip + (size_t)b * 64 * T_LEN + t;
    #pragma unroll
    for (int s = 0; s < 64; ++s) {
        float v = srow[(size_t)s * T_LEN] * scale;
        rbuf[s] = v > 0.f ? v : 0.f;
    }
    float oacc = l2b[0];
    for (int cch = 0; cch < 64; ++cch) {
        float a = l1b[cch];
        const float* wrow = l1w + (size_t)cch * 64;
        #pragma unroll
        for (int s = 0; s < 64; ++s) a = fmaf(wrow[s], rbuf[s], a);
        a = a > 0.f ? a : 0.f;
        oacc = fmaf(l2w[cch], a, oacc);
    }
    out[idx] = oacc;
}

// ---------------- launch ----------------
extern "C" void kernel_launch(void* const* d_in, const int* in_sizes, int n_in,
                              void* d_out, int out_size, void* d_ws, size_t ws_size,
                              hipStream_t stream) {
    const float* c          = (const float*)d_in[0];
    const float* noise      = (const float*)d_in[1];
    const float* first_w    = (const float*)d_in[2];
    const float* first_b    = (const float*)d_in[3];
    const float* up_in_w    = (const float*)d_in[4];
    const float* up_conv_w  = (const float*)d_in[5];
    const float* blk_conv_w = (const float*)d_in[6];
    const float* blk_conv_b = (const float*)d_in[7];
    const float* blk_aux_w  = (const float*)d_in[8];
    const float* blk_out_w  = (const float*)d_in[9];
    const float* blk_out_b  = (const float*)d_in[10];
    const float* blk_skip_w = (const float*)d_in[11];
    const float* blk_skip_b = (const float*)d_in[12];
    const float* last1_w    = (const float*)d_in[13];
    const float* last1_b    = (const float*)d_in[14];
    const float* last2_w    = (const float*)d_in[15];
    const float* last2_b    = (const float*)d_in[16];
    float* out = (float*)d_out;
    float* ws  = (float*)d_ws;

    size_t off = 0;
    float* cu0  = ws + off; off += 96256;
    float* g    = ws + off; off += 30ull * 4 * 128 * T_MEL;
    float* filt = ws + off; off += 128;
    float* xA   = ws + off; off += 4ull * 64 * T_LEN;
    float* xB   = ws + off; off += 4ull * 64 * T_LEN;
    float* skip = ws + off; off += 4ull * 64 * T_LEN;
    if (ws_size < off * sizeof(float)) return;

    hipLaunchKernelGGL(cu0_kernel, dim3((B_N * 80 * T_MEL + 255) / 256), dim3(256), 0, stream,
                       c, up_in_w, cu0);
    hipLaunchKernelGGL(filt_kernel, dim3(1), dim3(64), 0, stream, up_conv_w, filt);
    hipLaunchKernelGGL(g_kernel, dim3((30 * B_N * 128 * T_MEL + 255) / 256), dim3(256), 0, stream,
                       cu0, blk_aux_w, g);
    hipLaunchKernelGGL(first_kernel, dim3((B_N * 64 * T_LEN + 255) / 256), dim3(256), 0, stream,
                       noise, first_w, first_b, xA);

    for (int i = 0; i < 30; ++i) {
        int dd = 1 << (i % 10);
        const float* xin = (i & 1) ? xB : xA;
        float* xout      = (i & 1) ? xA : xB;
        hipLaunchKernelGGL(block_kernel, dim3(T_LEN / 128, B_N), dim3(256), 0, stream,
                           xin, xout, skip,
                           g + (size_t)i * 4 * 128 * T_MEL, filt,
                           blk_conv_w + (size_t)i * 128 * 64 * 3,
                           blk_conv_b + (size_t)i * 128,
                           blk_skip_w + (size_t)i * 64 * 64,
                           blk_skip_b + (size_t)i * 64,
                           blk_out_w + (size_t)i * 64 * 64,
                           blk_out_b + (size_t)i * 64,
                           dd, i == 0 ? 1 : 0);
    }

    hipLaunchKernelGGL(final_kernel, dim3((B_N * T_LEN + 255) / 256), dim3(256), 0, stream,
                       skip, last1_w, last1_b, last2_w, last2_b, out);
}